// Round 1
// baseline (9206.580 us; speedup 1.0000x reference)
//
#include <hip/hip_runtime.h>
#include <hip/hip_bf16.h>

#define B_   4
#define T_   16384
#define CH_  128
#define TCH_ 256
#define KS_  3
#define NL_  10
#define TT_  64

// ---------------------------------------------------------------------------
// Prep: transpose weights so the o-dimension is contiguous (enables wave-
// uniform s_load_dwordx4 in the inner loops).
//   wTconv[li][c][k][o] = conv_w[li][o][c][k]      (10*128*3*256 floats)
//   wT1[li][c][o]       = w1x1[li][o][c]           (10*128*128 floats)
// ---------------------------------------------------------------------------
__global__ __launch_bounds__(256) void transpose_w(
    const float* __restrict__ conv_w, const float* __restrict__ w1x1,
    float* __restrict__ wTconv, float* __restrict__ wT1) {
  int idx = blockIdx.x * 256 + threadIdx.x;
  const int NC = NL_ * CH_ * KS_ * TCH_;  // 983040
  if (idx < NC) {
    int o = idx % TCH_;
    int r = idx / TCH_;
    int k = r % KS_;  r /= KS_;
    int c = r % CH_;
    int li = r / CH_;
    wTconv[idx] = conv_w[((li * TCH_ + o) * CH_ + c) * KS_ + k];
  } else {
    int j = idx - NC;
    if (j < NL_ * CH_ * CH_) {
      int o = j % CH_;
      int r = j / CH_;
      int c = r % CH_;
      int li = r / CH_;
      wT1[j] = w1x1[(li * CH_ + o) * CH_ + c];
    }
  }
}

// ---------------------------------------------------------------------------
// Rechannel: h0[b][ch][t] = w_re[ch] * x[b][t];  head = head_init (zeros).
// ---------------------------------------------------------------------------
__global__ __launch_bounds__(256) void rechannel_k(
    const float* __restrict__ x, const float* __restrict__ head_init,
    const float* __restrict__ w_re,
    float* __restrict__ h0, float* __restrict__ head) {
  int i4 = blockIdx.x * 256 + threadIdx.x;  // float4 index
  int flat = i4 * 4;                        // < 2^31
  int b = flat / (CH_ * T_);
  int ch = (flat / T_) % CH_;
  int t = flat % T_;
  float w = w_re[ch];
  const float4 xv = *(const float4*)(x + b * T_ + t);
  float4 hv = make_float4(w * xv.x, w * xv.y, w * xv.z, w * xv.w);
  *(float4*)(h0 + flat) = hv;
  *(float4*)(head + flat) = *(const float4*)(head_init + flat);
}

// ---------------------------------------------------------------------------
// One dilated layer, fully fused:
//   z[o,t]   = conv_b[o] + mix_w[o]*c[t] + sum_{c,k} w[o,c,k]*h[c, t-(2-k)d]
//   post     = tanh(z[:128]) * sigmoid(z[128:])
//   head    += post
//   hout[o]  = hin[o] + b1x1[o] + sum_c w1x1[o,c]*post[c]
// Block: (t-tile of 64, batch b). 256 threads = 4 waves.
// Wave w owns gate-pairs p in [32w, 32w+32): both halves (p, p+128) in-reg.
// LDS: hm[3][128][64] fp32 (96KB) + post[128][64] (32KB) = 128KB.
// ---------------------------------------------------------------------------
__global__ __launch_bounds__(256) void layer_k(
    const float* __restrict__ hin, float* __restrict__ hout,
    float* __restrict__ head, const float* __restrict__ cin,
    const float* __restrict__ wT,     // [128][3][256] this layer
    const float* __restrict__ bconv,  // [256]
    const float* __restrict__ wmix,   // [256]
    const float* __restrict__ w1T,    // [128][128] (c, o)
    const float* __restrict__ b1,     // [128]
    int d) {
  __shared__ float hm[3 * CH_ * TT_];     // [k][c][tt]
  __shared__ float post_sh[CH_ * TT_];    // [c][tt]

  const int b = blockIdx.y;
  const int t0 = blockIdx.x * TT_;
  const int tid = threadIdx.x;

  // ---- stage 3 shifted h tiles (coalesced in t; causal zero-pad left) ----
  for (int idx = tid; idx < 3 * CH_ * TT_; idx += 256) {
    int k = idx / (CH_ * TT_);
    int rem = idx - k * (CH_ * TT_);
    int c = rem / TT_;
    int tt = rem - c * TT_;
    int t = t0 + tt - (2 - k) * d;
    hm[idx] = (t >= 0) ? hin[(b * CH_ + c) * T_ + t] : 0.0f;
  }
  __syncthreads();

  const int wave = __builtin_amdgcn_readfirstlane(tid >> 6);  // uniform
  const int lane = tid & 63;
  const int t = t0 + lane;
  const int wbase = wave * 32;
  const float cv = cin[b * T_ + t];

  // ---- dilated conv + gating + head update ----
  for (int pg = 0; pg < 32; pg += 4) {
    const int p0 = wbase + pg;
    float aLo[4] = {0.f, 0.f, 0.f, 0.f};
    float aHi[4] = {0.f, 0.f, 0.f, 0.f};
#pragma unroll 4
    for (int c = 0; c < CH_; ++c) {
#pragma unroll
      for (int k = 0; k < KS_; ++k) {
        float v = hm[(k * CH_ + c) * TT_ + lane];
        const float* wp = wT + (c * KS_ + k) * TCH_ + p0;  // uniform -> s_load
#pragma unroll
        for (int j = 0; j < 4; ++j) {
          aLo[j] += wp[j] * v;
          aHi[j] += wp[CH_ + j] * v;
        }
      }
    }
#pragma unroll
    for (int j = 0; j < 4; ++j) {
      int o = p0 + j;
      float zl = aLo[j] + bconv[o] + wmix[o] * cv;
      float zh = aHi[j] + bconv[CH_ + o] + wmix[CH_ + o] * cv;
      float pz = tanhf(zl) * (1.0f / (1.0f + expf(-zh)));
      post_sh[o * TT_ + lane] = pz;
      head[(b * CH_ + o) * T_ + t] += pz;  // one thread per location
    }
  }
  __syncthreads();

  // ---- 1x1 residual ----
  for (int og = 0; og < 32; og += 8) {
    const int o0 = wbase + og;
    float acc[8];
#pragma unroll
    for (int j = 0; j < 8; ++j)
      acc[j] = b1[o0 + j] + hm[(2 * CH_ + (o0 + j)) * TT_ + lane];  // center tap = hin
#pragma unroll 4
    for (int c = 0; c < CH_; ++c) {
      float v = post_sh[c * TT_ + lane];
      const float* wp = w1T + c * CH_ + o0;  // uniform -> s_load
#pragma unroll
      for (int j = 0; j < 8; ++j) acc[j] += wp[j] * v;
    }
#pragma unroll
    for (int j = 0; j < 8; ++j)
      hout[(b * CH_ + o0 + j) * T_ + t] = acc[j];
  }
}

// ---------------------------------------------------------------------------
// Head: out[b][t] = b_head + sum_c w_head[c] * head[b][c][t]
// ---------------------------------------------------------------------------
__global__ __launch_bounds__(256) void head_k(
    const float* __restrict__ head, const float* __restrict__ w_head,
    const float* __restrict__ b_head, float* __restrict__ out) {
  int idx = blockIdx.x * 256 + threadIdx.x;  // over B*T
  int b = idx / T_;
  int t = idx - b * T_;
  float acc = b_head[0];
#pragma unroll 8
  for (int c = 0; c < CH_; ++c)
    acc += w_head[c] * head[(b * CH_ + c) * T_ + t];
  out[idx] = acc;
}

extern "C" void kernel_launch(void* const* d_in, const int* in_sizes, int n_in,
                              void* d_out, int out_size, void* d_ws, size_t ws_size,
                              hipStream_t stream) {
  const float* x         = (const float*)d_in[0];
  const float* c         = (const float*)d_in[1];
  const float* head_init = (const float*)d_in[2];
  const float* w_re      = (const float*)d_in[3];
  const float* conv_w    = (const float*)d_in[4];
  const float* conv_b    = (const float*)d_in[5];
  const float* mix_w     = (const float*)d_in[6];
  const float* w1x1      = (const float*)d_in[7];
  const float* b1x1      = (const float*)d_in[8];
  const float* w_head    = (const float*)d_in[9];
  const float* b_head    = (const float*)d_in[10];

  float* out = (float*)d_out;            // [B*T]
  float* h_final = out + B_ * T_;        // [B*CH*T] — also ping buffer

  float* ws     = (float*)d_ws;
  float* hA     = ws;                    // 8388608 floats
  float* head   = ws + 8388608;          // 8388608 floats
  float* wTconv = ws + 2 * 8388608;      // 983040 floats
  float* wT1    = wTconv + NL_ * CH_ * KS_ * TCH_;  // 163840 floats

  const int n_tw = NL_ * CH_ * KS_ * TCH_ + NL_ * CH_ * CH_;  // 1146880
  transpose_w<<<(n_tw + 255) / 256, 256, 0, stream>>>(conv_w, w1x1, wTconv, wT1);

  rechannel_k<<<(B_ * CH_ * T_) / 4 / 256, 256, 0, stream>>>(
      x, head_init, w_re, h_final, head);

  const int dil[NL_] = {1, 2, 4, 8, 16, 32, 64, 128, 256, 512};
  for (int li = 0; li < NL_; ++li) {
    const float* hin = (li & 1) ? hA : h_final;   // L0 reads h_final (h0)
    float* hout      = (li & 1) ? h_final : hA;   // L9 (odd) writes h_final ✓
    layer_k<<<dim3(T_ / TT_, B_), 256, 0, stream>>>(
        hin, hout, head, c,
        wTconv + li * CH_ * KS_ * TCH_,
        conv_b + li * TCH_,
        mix_w + li * TCH_,
        wT1 + li * CH_ * CH_,
        b1x1 + li * CH_,
        dil[li]);
  }

  head_k<<<(B_ * T_) / 256, 256, 0, stream>>>(head, w_head, b_head, out);
}

// Round 2
// 548.001 us; speedup vs baseline: 16.8003x; 16.8003x over previous
//
#include <hip/hip_runtime.h>
#include <hip/hip_bf16.h>

#define B_   4
#define T_   16384
#define CH_  128
#define TCH_ 256
#define NL_  10
#define TT_  64
#define KC_  384          // conv GEMM K = 128 ch * 3 taps (ck = k*128 + c)
#define SHW_ 196          // H LDS row stride in dwords (392 bf16, pad 384+8)
#define SPW_ 68           // post LDS row stride in dwords (136 bf16, pad 128+8)

typedef __attribute__((ext_vector_type(8))) short short8;
typedef __attribute__((ext_vector_type(4))) float f32x4;

#define MFMA16(a, b, c) __builtin_amdgcn_mfma_f32_16x16x32_bf16(a, b, c, 0, 0, 0)

__device__ __forceinline__ unsigned short f2bf(float f) {
  unsigned u = __float_as_uint(f);
  return (unsigned short)((u + 0x7FFFu + ((u >> 16) & 1u)) >> 16);
}
__device__ __forceinline__ float bf2f(unsigned s) {
  return __uint_as_float((s & 0xFFFFu) << 16);
}
__device__ __forceinline__ float fast_tanh(float x) {
  float e = __expf(2.0f * fabsf(x));          // inf-safe: e=inf -> t=1
  float t = 1.0f - 2.0f / (e + 1.0f);
  return copysignf(t, x);
}
__device__ __forceinline__ float fast_sig(float x) {
  return 1.0f / (1.0f + __expf(-x));
}

// ---------------------------------------------------------------------------
// Prep: pack weights (bf16) into per-wave MFMA A-fragment order.
// conv: wpackA[li][w][f][ks][lane][j], f: 0=lo p0,1=lo p1,2=hi p0,3=hi p1
//   o = 32w + 16(f&1) + 128(f>>1) + (lane%16); ck = 32ks + 8(lane/16) + j
//   ck = k*128 + c  (k-major)
// 1x1: wpack1[li][w][p][ks][lane][j]: o = 32w+16p+(lane%16); c = 32ks+8(lane/16)+j
// ---------------------------------------------------------------------------
__global__ __launch_bounds__(256) void pack_w(
    const float* __restrict__ conv_w, const float* __restrict__ w1x1,
    unsigned short* __restrict__ wpackA, unsigned short* __restrict__ wpack1) {
  const int NA = NL_ * 4 * 4 * 12 * 64 * 8;  // 983040
  int idx = blockIdx.x * 256 + threadIdx.x;
  if (idx < NA) {
    int j = idx & 7;
    int t1 = idx >> 3;
    int l = t1 & 63;
    int t2 = t1 >> 6;
    int ks = t2 % 12;
    int t3 = t2 / 12;
    int f = t3 & 3;
    int t4 = t3 >> 2;
    int w = t4 & 3;
    int li = t4 >> 2;
    int o = 32 * w + 16 * (f & 1) + 128 * (f >> 1) + (l & 15);
    int ck = 32 * ks + 8 * (l >> 4) + j;
    int c = ck & 127, k = ck >> 7;
    wpackA[idx] = f2bf(conv_w[((li * TCH_ + o) * CH_ + c) * 3 + k]);
  } else {
    int i2 = idx - NA;
    if (i2 < NL_ * 4 * 2 * 4 * 64 * 8) {
      int j = i2 & 7;
      int t1 = i2 >> 3;
      int l = t1 & 63;
      int t2 = t1 >> 6;
      int ks = t2 & 3;
      int t3 = t2 >> 2;
      int p = t3 & 1;
      int t4 = t3 >> 1;
      int w = t4 & 3;
      int li = t4 >> 2;
      int o = 32 * w + 16 * p + (l & 15);
      int c = 32 * ks + 8 * (l >> 4) + j;
      wpack1[i2] = f2bf(w1x1[(li * CH_ + o) * CH_ + c]);
    }
  }
}

// ---------------------------------------------------------------------------
// Rechannel: h0[b][ch][t] = w_re[ch] * x[b][t]
// ---------------------------------------------------------------------------
__global__ __launch_bounds__(256) void rechannel_k(
    const float* __restrict__ x, const float* __restrict__ w_re,
    float* __restrict__ h0) {
  int i4 = blockIdx.x * 256 + threadIdx.x;
  int flat = i4 * 4;
  int b = flat / (CH_ * T_);
  int ch = (flat / T_) % CH_;
  int t = flat % T_;
  float w = w_re[ch];
  const float4 xv = *(const float4*)(x + b * T_ + t);
  *(float4*)(h0 + flat) = make_float4(w * xv.x, w * xv.y, w * xv.z, w * xv.w);
}

// ---------------------------------------------------------------------------
// out_init: out[b][t] = b_head + sum_c w_head[c]*head_init[b][c][t]
// ---------------------------------------------------------------------------
__global__ __launch_bounds__(256) void out_init_k(
    const float* __restrict__ head_init, const float* __restrict__ w_head,
    const float* __restrict__ b_head, float* __restrict__ out) {
  int idx = blockIdx.x * 256 + threadIdx.x;  // over B*T
  int b = idx / T_;
  int t = idx - b * T_;
  float acc = b_head[0];
#pragma unroll 8
  for (int c = 0; c < CH_; ++c)
    acc += w_head[c] * head_init[(b * CH_ + c) * T_ + t];
  out[idx] = acc;
}

// ---------------------------------------------------------------------------
// One fused layer (MFMA):
//  conv GEMM z[256 x 64] = W[256 x 384] * H[384 x 64]  (K = ck = k*128+c)
//  gating in-register (wave owns o-pairs), post -> LDS bf16
//  1x1 GEMM delta[128 x 64] = W1[128 x 128] * post; hout = hin + b1 + delta
//  out[b][t] += sum_c w_head[c] * post[c][t]
// Block: 256 thr = 4 waves, t-tile 64, grid (T/64, B).
// ---------------------------------------------------------------------------
__global__ __launch_bounds__(256, 2) void layer_k(
    const float* __restrict__ hin, float* __restrict__ hout,
    const float* __restrict__ cin, float* __restrict__ out,
    const unsigned short* __restrict__ wA,   // conv A-frag pack (this layer)
    const unsigned short* __restrict__ w1p,  // 1x1 A-frag pack (this layer)
    const float* __restrict__ bconv,         // [256]
    const float* __restrict__ wmix,          // [256]
    const float* __restrict__ b1,            // [128]
    const float* __restrict__ w_head,        // [128]
    int d) {
  __shared__ unsigned shH[TT_ * SHW_];  // H tile  [tt][392 bf16]  (50176 B)
  __shared__ unsigned shP[TT_ * SPW_];  // post    [tt][136 bf16]  (17408 B)
  __shared__ float shR[256];            // head-partial reduce

  const int tid = threadIdx.x;
  const int b = blockIdx.y;
  const int t0 = blockIdx.x * TT_;

  // ---- stage H as bf16: shH[tt][k*128+c] = h[c][t0+tt-(2-k)d] ----
#pragma unroll 4
  for (int it = 0; it < 48; ++it) {
    int flat = it * 256 + tid;
    int tt = flat & 63;
    int cp = (flat >> 6) & 63;   // channel pair
    int k = flat >> 12;          // 0..2
    int t = t0 + tt - (2 - k) * d;
    float f0 = 0.f, f1 = 0.f;
    if (t >= 0) {
      const float* hp = hin + ((b * CH_ + 2 * cp) * T_ + t);
      f0 = hp[0];
      f1 = hp[T_];
    }
    shH[tt * SHW_ + k * 64 + cp] =
        (unsigned)f2bf(f0) | ((unsigned)f2bf(f1) << 16);
  }
  __syncthreads();

  const int wave = __builtin_amdgcn_readfirstlane(tid >> 6);
  const int lane = tid & 63;
  const int r = lane & 15;
  const int g = lane >> 4;

  // ---- conv GEMM: 12 K-steps, per wave 4 o-frags x 4 t-frags ----
  f32x4 accL[2][4], accH[2][4];
#pragma unroll
  for (int p = 0; p < 2; ++p)
#pragma unroll
    for (int q = 0; q < 4; ++q) {
      accL[p][q] = (f32x4){0.f, 0.f, 0.f, 0.f};
      accH[p][q] = (f32x4){0.f, 0.f, 0.f, 0.f};
    }

  const short8* wAv = (const short8*)wA;
#pragma unroll
  for (int ks = 0; ks < 12; ++ks) {
    short8 bf[4];
#pragma unroll
    for (int q = 0; q < 4; ++q)
      bf[q] = *(const short8*)(shH + (16 * q + r) * SHW_ + 16 * ks + 4 * g);
    short8 a0 = wAv[((wave * 4 + 0) * 12 + ks) * 64 + lane];
    short8 a1 = wAv[((wave * 4 + 1) * 12 + ks) * 64 + lane];
    short8 a2 = wAv[((wave * 4 + 2) * 12 + ks) * 64 + lane];
    short8 a3 = wAv[((wave * 4 + 3) * 12 + ks) * 64 + lane];
#pragma unroll
    for (int q = 0; q < 4; ++q) {
      accL[0][q] = MFMA16(a0, bf[q], accL[0][q]);
      accL[1][q] = MFMA16(a1, bf[q], accL[1][q]);
      accH[0][q] = MFMA16(a2, bf[q], accH[0][q]);
      accH[1][q] = MFMA16(a3, bf[q], accH[1][q]);
    }
  }

  // ---- gating (in-register: pair (o, o+128) same lane/reg) ----
  float cq[4];
#pragma unroll
  for (int q = 0; q < 4; ++q) cq[q] = cin[b * T_ + t0 + 16 * q + r];

#pragma unroll
  for (int p = 0; p < 2; ++p) {
    float bcL[4], bcH[4], wmL[4], wmH[4];
#pragma unroll
    for (int j = 0; j < 4; ++j) {
      int o = 32 * wave + 16 * p + 4 * g + j;
      bcL[j] = bconv[o];
      bcH[j] = bconv[o + CH_];
      wmL[j] = wmix[o];
      wmH[j] = wmix[o + CH_];
    }
#pragma unroll
    for (int q = 0; q < 4; ++q) {
      float pv[4];
#pragma unroll
      for (int j = 0; j < 4; ++j) {
        float zl = accL[p][q][j] + bcL[j] + wmL[j] * cq[q];
        float zh = accH[p][q][j] + bcH[j] + wmH[j] * cq[q];
        pv[j] = fast_tanh(zl) * fast_sig(zh);
      }
      uint2 pk;
      pk.x = (unsigned)f2bf(pv[0]) | ((unsigned)f2bf(pv[1]) << 16);
      pk.y = (unsigned)f2bf(pv[2]) | ((unsigned)f2bf(pv[3]) << 16);
      // post[t][c], c = 32*wave + 16*p + 4*g + (0..3)
      *(uint2*)(shP + (16 * q + r) * SPW_ + 16 * wave + 8 * p + 2 * g) = pk;
    }
  }
  __syncthreads();

  // ---- 1x1 GEMM: delta[128 x 64] = W1 * post ----
  f32x4 acc2[2][4];
#pragma unroll
  for (int p = 0; p < 2; ++p)
#pragma unroll
    for (int q = 0; q < 4; ++q) acc2[p][q] = (f32x4){0.f, 0.f, 0.f, 0.f};

  const short8* w1v = (const short8*)w1p;
#pragma unroll
  for (int ks = 0; ks < 4; ++ks) {
    short8 bp[4];
#pragma unroll
    for (int q = 0; q < 4; ++q)
      bp[q] = *(const short8*)(shP + (16 * q + r) * SPW_ + 16 * ks + 4 * g);
    short8 a0 = w1v[((wave * 2 + 0) * 4 + ks) * 64 + lane];
    short8 a1 = w1v[((wave * 2 + 1) * 4 + ks) * 64 + lane];
#pragma unroll
    for (int q = 0; q < 4; ++q) {
      acc2[0][q] = MFMA16(a0, bp[q], acc2[0][q]);
      acc2[1][q] = MFMA16(a1, bp[q], acc2[1][q]);
    }
  }

  // ---- residual write (fp32 path: re-read hin) ----
#pragma unroll
  for (int p = 0; p < 2; ++p) {
    float b1v[4];
#pragma unroll
    for (int j = 0; j < 4; ++j) b1v[j] = b1[32 * wave + 16 * p + 4 * g + j];
#pragma unroll
    for (int q = 0; q < 4; ++q) {
#pragma unroll
      for (int j = 0; j < 4; ++j) {
        int o = 32 * wave + 16 * p + 4 * g + j;
        int gi = (b * CH_ + o) * T_ + t0 + 16 * q + r;
        hout[gi] = hin[gi] + b1v[j] + acc2[p][q][j];
      }
    }
  }

  // ---- head contribution: out[b][t] += sum_c w_head[c]*post[c][t] ----
  {
    int tt = tid & 63;
    int qr = tid >> 6;
    float s = 0.f;
#pragma unroll
    for (int i = 0; i < 8; ++i) {
      int c0 = qr * 32 + i * 4;
      uint2 v = *(const uint2*)(shP + tt * SPW_ + (c0 >> 1));
      s += w_head[c0] * bf2f(v.x) + w_head[c0 + 1] * bf2f(v.x >> 16) +
           w_head[c0 + 2] * bf2f(v.y) + w_head[c0 + 3] * bf2f(v.y >> 16);
    }
    shR[qr * 64 + tt] = s;
  }
  __syncthreads();
  if (tid < 64) {
    float tot = shR[tid] + shR[64 + tid] + shR[128 + tid] + shR[192 + tid];
    out[b * T_ + t0 + tid] += tot;
  }
}

extern "C" void kernel_launch(void* const* d_in, const int* in_sizes, int n_in,
                              void* d_out, int out_size, void* d_ws, size_t ws_size,
                              hipStream_t stream) {
  const float* x         = (const float*)d_in[0];
  const float* c         = (const float*)d_in[1];
  const float* head_init = (const float*)d_in[2];
  const float* w_re      = (const float*)d_in[3];
  const float* conv_w    = (const float*)d_in[4];
  const float* conv_b    = (const float*)d_in[5];
  const float* mix_w     = (const float*)d_in[6];
  const float* w1x1      = (const float*)d_in[7];
  const float* b1x1      = (const float*)d_in[8];
  const float* w_head    = (const float*)d_in[9];
  const float* b_head    = (const float*)d_in[10];

  float* out = (float*)d_out;          // [B*T]
  float* hX  = out + B_ * T_;          // h region of d_out (ping X)

  float* hY = (float*)d_ws;            // ping Y (8388608 floats)
  unsigned short* wpackA = (unsigned short*)(hY + 8388608);   // 983040
  unsigned short* wpack1 = wpackA + NL_ * 4 * 4 * 12 * 64 * 8;  // 163840

  const int n_pack = NL_ * 4 * 4 * 12 * 64 * 8 + NL_ * 4 * 2 * 4 * 64 * 8;
  pack_w<<<(n_pack + 255) / 256, 256, 0, stream>>>(conv_w, w1x1, wpackA, wpack1);

  rechannel_k<<<(B_ * CH_ * T_) / 4 / 256, 256, 0, stream>>>(x, w_re, hX);
  out_init_k<<<(B_ * T_) / 256, 256, 0, stream>>>(head_init, w_head, b_head, out);

  const int dil[NL_] = {1, 2, 4, 8, 16, 32, 64, 128, 256, 512};
  for (int li = 0; li < NL_; ++li) {
    const float* hin = (li & 1) ? hY : hX;  // L0: X -> Y, L1: Y -> X, ... L9 -> X
    float* ho        = (li & 1) ? hX : hY;
    layer_k<<<dim3(T_ / TT_, B_), 256, 0, stream>>>(
        hin, ho, c, out,
        wpackA + li * (4 * 4 * 12 * 64 * 8),
        wpack1 + li * (4 * 2 * 4 * 64 * 8),
        conv_b + li * TCH_,
        mix_w + li * TCH_,
        b1x1 + li * CH_,
        w_head,
        dil[li]);
  }
}

// Round 3
// 324.680 us; speedup vs baseline: 28.3558x; 1.6878x over previous
//
#include <hip/hip_runtime.h>
#include <hip/hip_bf16.h>

#define B_   4
#define T_   16384
#define CH_  128
#define TCH_ 256
#define NL_  10
#define TT_  64
#define SHW_ 196          // shH row stride in dwords (384 bf16 + 8 pad)
#define SPW_ 68           // shP row stride in dwords (128 bf16 + 8 pad)

typedef __attribute__((ext_vector_type(8))) short short8;
typedef __attribute__((ext_vector_type(4))) float f32x4;

#define MFMA16(a, b, c) __builtin_amdgcn_mfma_f32_16x16x32_bf16(a, b, c, 0, 0, 0)

__device__ __forceinline__ unsigned short f2bf(float f) {
  unsigned u = __float_as_uint(f);
  return (unsigned short)((u + 0x7FFFu + ((u >> 16) & 1u)) >> 16);
}
__device__ __forceinline__ float bf2f(unsigned s) {
  return __uint_as_float((s & 0xFFFFu) << 16);
}
__device__ __forceinline__ float fast_tanh(float x) {
  float e = __expf(2.0f * fabsf(x));  // inf-safe: e=inf -> t=1
  float t = 1.0f - 2.0f / (e + 1.0f);
  return copysignf(t, x);
}
__device__ __forceinline__ float fast_sig(float x) {
  return 1.0f / (1.0f + __expf(-x));
}

// ---------------------------------------------------------------------------
// Prep: pack weights (bf16) into per-wave MFMA A-fragment order (unchanged
// from round 2 — the LDS ck layout k*128+c is preserved).
// ---------------------------------------------------------------------------
__global__ __launch_bounds__(256) void pack_w(
    const float* __restrict__ conv_w, const float* __restrict__ w1x1,
    unsigned short* __restrict__ wpackA, unsigned short* __restrict__ wpack1) {
  const int NA = NL_ * 4 * 4 * 12 * 64 * 8;  // 983040
  int idx = blockIdx.x * 256 + threadIdx.x;
  if (idx < NA) {
    int j = idx & 7;
    int t1 = idx >> 3;
    int l = t1 & 63;
    int t2 = t1 >> 6;
    int ks = t2 % 12;
    int t3 = t2 / 12;
    int f = t3 & 3;
    int t4 = t3 >> 2;
    int w = t4 & 3;
    int li = t4 >> 2;
    int o = 32 * w + 16 * (f & 1) + 128 * (f >> 1) + (l & 15);
    int ck = 32 * ks + 8 * (l >> 4) + j;
    int c = ck & 127, k = ck >> 7;
    wpackA[idx] = f2bf(conv_w[((li * TCH_ + o) * CH_ + c) * 3 + k]);
  } else {
    int i2 = idx - NA;
    if (i2 < NL_ * 4 * 2 * 4 * 64 * 8) {
      int j = i2 & 7;
      int t1 = i2 >> 3;
      int l = t1 & 63;
      int t2 = t1 >> 6;
      int ks = t2 & 3;
      int t3 = t2 >> 2;
      int p = t3 & 1;
      int t4 = t3 >> 1;
      int w = t4 & 3;
      int li = t4 >> 2;
      int o = 32 * w + 16 * p + (l & 15);
      int c = 32 * ks + 8 * (l >> 4) + j;
      wpack1[i2] = f2bf(w1x1[(li * CH_ + o) * CH_ + c]);
    }
  }
}

// ---------------------------------------------------------------------------
// Rechannel into bf16 [b][t][c]: hb[b][t][c] = bf16(w_re[c] * x[b][t])
// ---------------------------------------------------------------------------
__global__ __launch_bounds__(256) void rechannel_k(
    const float* __restrict__ x, const float* __restrict__ w_re,
    unsigned short* __restrict__ hb) {
  int flat = blockIdx.x * 256 + threadIdx.x;  // B*T*16 chunks of 8 ch
  int cid = flat & 15;
  int t = (flat >> 4) & (T_ - 1);
  int b = flat >> 18;
  float xv = x[b * T_ + t];
  const float* wr = w_re + cid * 8;
  union { short8 s; unsigned short u[8]; } o;
#pragma unroll
  for (int j = 0; j < 8; ++j) o.u[j] = f2bf(wr[j] * xv);
  *(short8*)(hb + (size_t)(b * T_ + t) * CH_ + cid * 8) = o.s;
}

// ---------------------------------------------------------------------------
// out_init: out[b][t] = b_head + sum_c w_head[c]*head_init[b][c][t]
// ---------------------------------------------------------------------------
__global__ __launch_bounds__(256) void out_init_k(
    const float* __restrict__ head_init, const float* __restrict__ w_head,
    const float* __restrict__ b_head, float* __restrict__ out) {
  int idx = blockIdx.x * 256 + threadIdx.x;  // over B*T
  int b = idx / T_;
  int t = idx - b * T_;
  float acc = b_head[0];
#pragma unroll 8
  for (int c = 0; c < CH_; ++c)
    acc += w_head[c] * head_init[(b * CH_ + c) * T_ + t];
  out[idx] = acc;
}

// ---------------------------------------------------------------------------
// One fused layer. h kept bf16 [b][t][c] between layers; layer 9 writes
// fp32 [b][c][t] into d_out. Residual base = LDS center tap (k=2 slab).
// Head contribution: in-register partials -> shfl reduce -> shR -> out +=.
// ---------------------------------------------------------------------------
__global__ __launch_bounds__(256, 2) void layer_k(
    const unsigned short* __restrict__ hin,  // bf16 [b][t][c]
    unsigned short* __restrict__ hob,        // bf16 [b][t][c] (layers 0..8)
    float* __restrict__ hof,                 // fp32 [b][c][t] (layer 9)
    const float* __restrict__ cin, float* __restrict__ out,
    const unsigned short* __restrict__ wA,   // conv A-frag pack (this layer)
    const unsigned short* __restrict__ w1p,  // 1x1 A-frag pack (this layer)
    const float* __restrict__ bconv,         // [256]
    const float* __restrict__ wmix,          // [256]
    const float* __restrict__ b1,            // [128]
    const float* __restrict__ w_head,        // [128]
    int d, int is_final) {
  __shared__ unsigned shH[TT_ * SHW_];  // [tt][k*128+c] bf16 (50176 B)
  __shared__ unsigned shP[TT_ * SPW_];  // [tt][c] bf16 post (17408 B)
  __shared__ float shR[4 * 4 * 16];     // [wave][q][r] head partials

  const int tid = threadIdx.x;
  const int b = blockIdx.y;
  const int t0 = blockIdx.x * TT_;

  // ---- stage H tiles (bf16, fully coalesced 16B chunks) ----
#pragma unroll
  for (int it = 0; it < 12; ++it) {
    int flat = it * 256 + tid;
    int cid = flat & 15;           // 16B chunk within row (8 channels)
    int tt = (flat >> 4) & 63;
    int k = flat >> 10;            // 0..2
    int t = t0 + tt - (2 - k) * d;
    uint4 v = make_uint4(0u, 0u, 0u, 0u);
    if (t >= 0)
      v = *(const uint4*)(hin + ((size_t)(b * T_ + t) * CH_ + cid * 8));
    *(uint4*)(shH + tt * SHW_ + k * 64 + cid * 4) = v;
  }
  __syncthreads();

  const int wave = __builtin_amdgcn_readfirstlane(tid >> 6);
  const int lane = tid & 63;
  const int r = lane & 15;
  const int g = lane >> 4;

  // ---- conv GEMM: z[256x64] = W[256x384] * H[384x64], 12 K-steps ----
  f32x4 accL[2][4], accH[2][4];
#pragma unroll
  for (int p = 0; p < 2; ++p)
#pragma unroll
    for (int q = 0; q < 4; ++q) {
      accL[p][q] = (f32x4){0.f, 0.f, 0.f, 0.f};
      accH[p][q] = (f32x4){0.f, 0.f, 0.f, 0.f};
    }

  const short8* wAv = (const short8*)wA;
#pragma unroll
  for (int ks = 0; ks < 12; ++ks) {
    short8 bf[4];
#pragma unroll
    for (int q = 0; q < 4; ++q)
      bf[q] = *(const short8*)(shH + (16 * q + r) * SHW_ + 16 * ks + 4 * g);
    short8 a0 = wAv[((wave * 4 + 0) * 12 + ks) * 64 + lane];
    short8 a1 = wAv[((wave * 4 + 1) * 12 + ks) * 64 + lane];
    short8 a2 = wAv[((wave * 4 + 2) * 12 + ks) * 64 + lane];
    short8 a3 = wAv[((wave * 4 + 3) * 12 + ks) * 64 + lane];
#pragma unroll
    for (int q = 0; q < 4; ++q) {
      accL[0][q] = MFMA16(a0, bf[q], accL[0][q]);
      accL[1][q] = MFMA16(a1, bf[q], accL[1][q]);
      accH[0][q] = MFMA16(a2, bf[q], accH[0][q]);
      accH[1][q] = MFMA16(a3, bf[q], accH[1][q]);
    }
  }

  // ---- gating + in-register head partials ----
  float cq[4];
#pragma unroll
  for (int q = 0; q < 4; ++q) cq[q] = cin[b * T_ + t0 + 16 * q + r];

  float hs[4] = {0.f, 0.f, 0.f, 0.f};
#pragma unroll
  for (int p = 0; p < 2; ++p) {
    float bcL[4], bcH[4], wmL[4], wmH[4], whv[4];
#pragma unroll
    for (int j = 0; j < 4; ++j) {
      int o = 32 * wave + 16 * p + 4 * g + j;
      bcL[j] = bconv[o];
      bcH[j] = bconv[o + CH_];
      wmL[j] = wmix[o];
      wmH[j] = wmix[o + CH_];
      whv[j] = w_head[o];
    }
#pragma unroll
    for (int q = 0; q < 4; ++q) {
      float pv[4];
#pragma unroll
      for (int j = 0; j < 4; ++j) {
        float zl = accL[p][q][j] + bcL[j] + wmL[j] * cq[q];
        float zh = accH[p][q][j] + bcH[j] + wmH[j] * cq[q];
        pv[j] = fast_tanh(zl) * fast_sig(zh);
        hs[q] += whv[j] * pv[j];
      }
      uint2 pk;
      pk.x = (unsigned)f2bf(pv[0]) | ((unsigned)f2bf(pv[1]) << 16);
      pk.y = (unsigned)f2bf(pv[2]) | ((unsigned)f2bf(pv[3]) << 16);
      *(uint2*)(shP + (16 * q + r) * SPW_ + 16 * wave + 8 * p + 2 * g) = pk;
    }
  }
  __syncthreads();

  // ---- 1x1 GEMM: delta[128x64] = W1 * post ----
  f32x4 acc2[2][4];
#pragma unroll
  for (int p = 0; p < 2; ++p)
#pragma unroll
    for (int q = 0; q < 4; ++q) acc2[p][q] = (f32x4){0.f, 0.f, 0.f, 0.f};

  const short8* w1v = (const short8*)w1p;
#pragma unroll
  for (int ks = 0; ks < 4; ++ks) {
    short8 bp[4];
#pragma unroll
    for (int q = 0; q < 4; ++q)
      bp[q] = *(const short8*)(shP + (16 * q + r) * SPW_ + 16 * ks + 4 * g);
    short8 a0 = w1v[((wave * 2 + 0) * 4 + ks) * 64 + lane];
    short8 a1 = w1v[((wave * 2 + 1) * 4 + ks) * 64 + lane];
#pragma unroll
    for (int q = 0; q < 4; ++q) {
      acc2[0][q] = MFMA16(a0, bp[q], acc2[0][q]);
      acc2[1][q] = MFMA16(a1, bp[q], acc2[1][q]);
    }
  }

  // ---- residual: res = hin(center tap, LDS) + b1 + delta ----
  float res[2][4][4];
  const int o0b = 32 * wave + 4 * g;
#pragma unroll
  for (int p = 0; p < 2; ++p) {
    const int o0 = o0b + 16 * p;
    float b1v[4];
#pragma unroll
    for (int j = 0; j < 4; ++j) b1v[j] = b1[o0 + j];
#pragma unroll
    for (int q = 0; q < 4; ++q) {
      uint2 hv = *(const uint2*)(shH + (16 * q + r) * SHW_ + 128 + (o0 >> 1));
      res[p][q][0] = bf2f(hv.x) + b1v[0] + acc2[p][q][0];
      res[p][q][1] = bf2f(hv.x >> 16) + b1v[1] + acc2[p][q][1];
      res[p][q][2] = bf2f(hv.y) + b1v[2] + acc2[p][q][2];
      res[p][q][3] = bf2f(hv.y >> 16) + b1v[3] + acc2[p][q][3];
    }
  }

  // ---- head partial reduce across g-groups, then waves ----
#pragma unroll
  for (int q = 0; q < 4; ++q) {
    hs[q] += __shfl_xor(hs[q], 16);
    hs[q] += __shfl_xor(hs[q], 32);
  }
  if (g == 0) {
#pragma unroll
    for (int q = 0; q < 4; ++q) shR[(wave * 4 + q) * 16 + r] = hs[q];
  }
  __syncthreads();  // shR ready; shH free for reuse

  if (tid < 64) {
    int q = tid >> 4, rr = tid & 15;
    float tot = shR[(0 * 4 + q) * 16 + rr] + shR[(1 * 4 + q) * 16 + rr] +
                shR[(2 * 4 + q) * 16 + rr] + shR[(3 * 4 + q) * 16 + rr];
    out[b * T_ + t0 + 16 * q + rr] += tot;
  }

  if (!is_final) {
    // stage hout tile (bf16) into shH cols 0..63 dwords, then coalesced copy
#pragma unroll
    for (int p = 0; p < 2; ++p) {
      const int o0 = o0b + 16 * p;
#pragma unroll
      for (int q = 0; q < 4; ++q) {
        uint2 pk;
        pk.x = (unsigned)f2bf(res[p][q][0]) | ((unsigned)f2bf(res[p][q][1]) << 16);
        pk.y = (unsigned)f2bf(res[p][q][2]) | ((unsigned)f2bf(res[p][q][3]) << 16);
        *(uint2*)(shH + (16 * q + r) * SHW_ + (o0 >> 1)) = pk;
      }
    }
    __syncthreads();
#pragma unroll
    for (int it = 0; it < 4; ++it) {
      int flat = it * 256 + tid;
      int cid = flat & 15;
      int tt = flat >> 4;
      *(uint4*)(hob + ((size_t)(b * T_ + t0 + tt) * CH_ + cid * 8)) =
          *(const uint4*)(shH + tt * SHW_ + cid * 4);
    }
  } else {
    // final layer: fp32 [b][c][t] into d_out
#pragma unroll
    for (int p = 0; p < 2; ++p) {
      const int o0 = o0b + 16 * p;
#pragma unroll
      for (int q = 0; q < 4; ++q) {
#pragma unroll
        for (int j = 0; j < 4; ++j)
          hof[(size_t)(b * CH_ + o0 + j) * T_ + t0 + 16 * q + r] = res[p][q][j];
      }
    }
  }
}

extern "C" void kernel_launch(void* const* d_in, const int* in_sizes, int n_in,
                              void* d_out, int out_size, void* d_ws, size_t ws_size,
                              hipStream_t stream) {
  const float* x         = (const float*)d_in[0];
  const float* c         = (const float*)d_in[1];
  const float* head_init = (const float*)d_in[2];
  const float* w_re      = (const float*)d_in[3];
  const float* conv_w    = (const float*)d_in[4];
  const float* conv_b    = (const float*)d_in[5];
  const float* mix_w     = (const float*)d_in[6];
  const float* w1x1      = (const float*)d_in[7];
  const float* b1x1      = (const float*)d_in[8];
  const float* w_head    = (const float*)d_in[9];
  const float* b_head    = (const float*)d_in[10];

  float* out = (float*)d_out;          // [B*T]
  float* hof = out + B_ * T_;          // fp32 h region of d_out

  unsigned short* hb0 = (unsigned short*)d_ws;          // bf16 h ping (16MB)
  unsigned short* hb1 = hb0 + (size_t)B_ * T_ * CH_;    // bf16 h pong (16MB)
  unsigned short* wpackA = hb1 + (size_t)B_ * T_ * CH_;
  unsigned short* wpack1 = wpackA + NL_ * 4 * 4 * 12 * 64 * 8;

  const int n_pack = NL_ * 4 * 4 * 12 * 64 * 8 + NL_ * 4 * 2 * 4 * 64 * 8;
  pack_w<<<(n_pack + 255) / 256, 256, 0, stream>>>(conv_w, w1x1, wpackA, wpack1);

  rechannel_k<<<(B_ * T_ * 16) / 256, 256, 0, stream>>>(x, w_re, hb0);
  out_init_k<<<(B_ * T_) / 256, 256, 0, stream>>>(head_init, w_head, b_head, out);

  const int dil[NL_] = {1, 2, 4, 8, 16, 32, 64, 128, 256, 512};
  for (int li = 0; li < NL_; ++li) {
    const unsigned short* hin = (li & 1) ? hb1 : hb0;
    unsigned short* hob       = (li & 1) ? hb0 : hb1;
    int is_final = (li == NL_ - 1);
    layer_k<<<dim3(T_ / TT_, B_), 256, 0, stream>>>(
        hin, hob, hof, c, out,
        wpackA + li * (4 * 4 * 12 * 64 * 8),
        wpack1 + li * (4 * 2 * 4 * 64 * 8),
        conv_b + li * TCH_,
        mix_w + li * TCH_,
        b1x1 + li * CH_,
        w_head,
        dil[li], is_final);
  }
}